// Round 1
// baseline (251.633 us; speedup 1.0000x reference)
//
#include <hip/hip_runtime.h>
#include <hip/hip_bf16.h>
#include <cstdint>

#define N_NODES 100000
#define HIDDEN  128
#define NEDGE   524288   // E (pos edges; neg same count)

typedef __attribute__((ext_vector_type(8))) short short8;
typedef __attribute__((ext_vector_type(4))) float f32x4;

__device__ __forceinline__ unsigned short f2b(float f) {
    unsigned u = __float_as_uint(f);
    u += 0x7FFFu + ((u >> 16) & 1u);   // RNE; inputs are finite
    return (unsigned short)(u >> 16);
}
__device__ __forceinline__ float b2f(unsigned x16) {
    return __uint_as_float(x16 << 16);
}

// A[m][n] = sum_k z[m][k] * W1[table*128 + k][n], stored as bf16.
// Tile: 64 rows x 128 cols per M-tile, 4 M-tiles per block. 4 waves, each
// wave does 16 rows x 128 cols = 8 N-tiles x 4 K-steps of mfma 16x16x32.
__global__ __launch_bounds__(256, 3)
void precompute_kernel(const float* __restrict__ z_src,
                       const float* __restrict__ z_dst,
                       const float* __restrict__ W1,
                       unsigned short* __restrict__ Asrc,
                       unsigned short* __restrict__ Adst)
{
    const int table = blockIdx.y;
    const float* z = table ? z_dst : z_src;
    const float* W = W1 + table * (128 * 128);
    unsigned short* A = table ? Adst : Asrc;

    // +8 bf16 pad per row: row stride 272 B -> bank shift 4/row, 2-way max (free)
    __shared__ unsigned short lds_wt[128 * 136]; // Wt[n][k] (transposed)
    __shared__ unsigned short lds_z[64 * 136];   // z-tile[m][k]

    const int tid = threadIdx.x;

    // Stage W-half transposed into LDS (once per block; one-time cost)
    for (int idx = tid; idx < 128 * 128; idx += 256) {
        int k = idx >> 7, n = idx & 127;            // coalesced global read
        lds_wt[n * 136 + k] = f2b(W[k * 128 + n]);
    }

    const int wave = tid >> 6;
    const int lane = tid & 63;
    const int t = lane & 15;   // m (A) / n (B) / col (D) index
    const int q = lane >> 4;   // K-chunk / row-quad

    for (int it = 0; it < 4; ++it) {
        const int m0 = (blockIdx.x * 4 + it) * 64;
        if (m0 >= N_NODES) break;                   // uniform across block
        __syncthreads();  // lds_z reuse safe; also covers W staging on it==0

        // Stage z tile: 64 rows x 128 f32 -> bf16 (coalesced float4 reads)
        for (int idx = tid; idx < 64 * 32; idx += 256) {
            int r = idx >> 5, c4 = idx & 31;
            int row = m0 + r;
            float4 v = make_float4(0.f, 0.f, 0.f, 0.f);
            if (row < N_NODES) v = *(const float4*)(z + (size_t)row * 128 + c4 * 4);
            ushort4 h;
            h.x = f2b(v.x); h.y = f2b(v.y); h.z = f2b(v.z); h.w = f2b(v.w);
            *(ushort4*)&lds_z[r * 136 + c4 * 4] = h;
        }
        __syncthreads();

        f32x4 acc[8];
#pragma unroll
        for (int n = 0; n < 8; ++n) acc[n] = (f32x4){0.f, 0.f, 0.f, 0.f};

#pragma unroll
        for (int ks = 0; ks < 4; ++ks) {
            const int k0 = ks * 32;
            // A frag: A[m=t][k0 + q*8 + j], 16B aligned (272B row stride)
            short8 a = *(const short8*)&lds_z[(wave * 16 + t) * 136 + k0 + q * 8];
#pragma unroll
            for (int n = 0; n < 8; ++n) {
                // B frag: B[k=k0+q*8+j][n=n*16+t] == Wt[n*16+t][k...]
                short8 b = *(const short8*)&lds_wt[(n * 16 + t) * 136 + k0 + q * 8];
                acc[n] = __builtin_amdgcn_mfma_f32_16x16x32_bf16(a, b, acc[n], 0, 0, 0);
            }
        }

        // D layout: col = lane&15 (=t), row = q*4 + reg
#pragma unroll
        for (int n = 0; n < 8; ++n) {
#pragma unroll
            for (int r = 0; r < 4; ++r) {
                int row = m0 + wave * 16 + q * 4 + r;
                if (row < N_NODES)
                    A[(size_t)row * 128 + n * 16 + t] = f2b(acc[n][r]);
            }
        }
    }
}

// 16 lanes per edge; each lane owns 8 hidden units (16B bf16 load per table).
// out[e] = sum_j relu(Asrc[s][j] + Adst[d][j] + b1[j]) * W2[j] + b2
__global__ __launch_bounds__(256, 6)
void edge_kernel(const unsigned short* __restrict__ Asrc,
                 const unsigned short* __restrict__ Adst,
                 const int* __restrict__ pos_src,
                 const int* __restrict__ pos_dst,
                 const int* __restrict__ neg_src,
                 const int* __restrict__ neg_dst,
                 const float* __restrict__ b1,
                 const float* __restrict__ W2,
                 const float* __restrict__ b2,
                 float* __restrict__ out)
{
    const int tid = threadIdx.x;
    const int t = tid & 15;      // lane-within-group: hidden slice t*8..t*8+7
    const int g = tid >> 4;      // edge group within block (0..15)

    float b1r[8], w2r[8];
#pragma unroll
    for (int j = 0; j < 8; ++j) {
        b1r[j] = b1[t * 8 + j];
        w2r[j] = W2[t * 8 + j];
    }
    const float bias2 = b2[0];

    const int ebase = blockIdx.x * 128;   // 8192 blocks x 128 edges = 2E exact
#pragma unroll 2
    for (int i = 0; i < 8; ++i) {
        const int e = ebase + i * 16 + g;
        int s, d;
        if (e < NEDGE) { s = pos_src[e]; d = pos_dst[e]; }
        else           { s = neg_src[e - NEDGE]; d = neg_dst[e - NEDGE]; }

        const uint4 ua = *(const uint4*)(Asrc + (size_t)s * 128 + t * 8);
        const uint4 ub = *(const uint4*)(Adst + (size_t)d * 128 + t * 8);

        float acc = 0.f;
        const unsigned* pa = (const unsigned*)&ua;
        const unsigned* pb = (const unsigned*)&ub;
#pragma unroll
        for (int j2 = 0; j2 < 4; ++j2) {
            float h0 = b2f(pa[j2] & 0xFFFFu) + b2f(pb[j2] & 0xFFFFu) + b1r[2 * j2];
            float h1 = b2f(pa[j2] >> 16)     + b2f(pb[j2] >> 16)     + b1r[2 * j2 + 1];
            h0 = fmaxf(h0, 0.f);
            h1 = fmaxf(h1, 0.f);
            acc = fmaf(h0, w2r[2 * j2], acc);
            acc = fmaf(h1, w2r[2 * j2 + 1], acc);
        }
        // reduce across the 16-lane group (xor masks < 16 stay in-group)
        acc += __shfl_xor(acc, 1);
        acc += __shfl_xor(acc, 2);
        acc += __shfl_xor(acc, 4);
        acc += __shfl_xor(acc, 8);
        if (t == 0) out[e] = acc + bias2;
    }
}

extern "C" void kernel_launch(void* const* d_in, const int* in_sizes, int n_in,
                              void* d_out, int out_size, void* d_ws, size_t ws_size,
                              hipStream_t stream) {
    const float* z_src  = (const float*)d_in[0];
    const float* z_dst  = (const float*)d_in[1];
    const int* pos_src  = (const int*)d_in[2];
    const int* pos_dst  = (const int*)d_in[3];
    const int* neg_src  = (const int*)d_in[4];
    const int* neg_dst  = (const int*)d_in[5];
    const float* W1     = (const float*)d_in[6];
    const float* b1     = (const float*)d_in[7];
    const float* W2     = (const float*)d_in[8];
    const float* b2     = (const float*)d_in[9];
    float* out = (float*)d_out;

    unsigned short* Asrc = (unsigned short*)d_ws;                 // 25.6 MB
    unsigned short* Adst = Asrc + (size_t)N_NODES * HIDDEN;       // 25.6 MB
    // total ws need: 51.2 MB

    dim3 pgrid(391, 2);  // ceil(1563 M-tiles / 4 per block), 2 tables
    precompute_kernel<<<pgrid, 256, 0, stream>>>(z_src, z_dst, W1, Asrc, Adst);

    edge_kernel<<<8192, 256, 0, stream>>>(Asrc, Adst, pos_src, pos_dst,
                                          neg_src, neg_dst, b1, W2, b2, out);
}